// Round 4
// baseline (385.908 us; speedup 1.0000x reference)
//
#include <hip/hip_runtime.h>
#include <stdint.h>

#define B_ 8
#define D_ 512
#define N_ 16384
#define K_ 32

typedef __attribute__((ext_vector_type(8))) short short8;
typedef __attribute__((ext_vector_type(16))) float f32x16;

union F8 { short8 v; unsigned short s[8]; uint32_t u[4]; uint4 q; };

// RNE pack of two fp32 -> bf16x2 in one u32
__device__ __forceinline__ uint32_t bfpack2(float lo, float hi) {
    uint32_t a = __float_as_uint(lo);
    uint32_t b = __float_as_uint(hi);
    a += 0x7FFFu + ((a >> 16) & 1u);
    b += 0x7FFFu + ((b >> 16) & 1u);
    return (a >> 16) | (b & 0xFFFF0000u);
}

// LDS-only barrier: waits lgkmcnt(0) but NOT vmcnt, so register-prefetch
// global loads stay in flight across workgroup barriers (avoids the
// compiler's full vmcnt(0) drain at __syncthreads, the m97-style stall).
// All in-loop barriers only order LDS data; prefetch targets private regs.
// imm 0xC07F: vmcnt[3:0]=0xF, expcnt=7, lgkmcnt=0, vmcnt[5:4]=3.
__device__ __forceinline__ void bar_lds() {
    __builtin_amdgcn_sched_barrier(0);
    __builtin_amdgcn_s_waitcnt(0xC07F);
    __builtin_amdgcn_s_barrier();
    __builtin_amdgcn_sched_barrier(0);
}

// Per block: 256 n (8 tiles of 32) x 512 d. X tile in LDS bf16 [d][n],
// rows padded to 40 u16 (16B-aligned b128 frags for GEMM2).
__launch_bounds__(256, 2)
__global__ void encode_kernel(const float* __restrict__ X,
                              const float* __restrict__ Cg,
                              const float* __restrict__ scale,
                              float* __restrict__ part,
                              float* __restrict__ aSumAcc)
{
    __shared__ uint32_t xsTw[D_ * 20];     // 40960 B: X^T tile bf16, row stride 40 u16
    __shared__ float    lgp[4][32][36];    // 18432 B: GEMM1 per-wave d-partials
    __shared__ uint32_t A_ldsw[K_ * 20];   //  2560 B: A bf16 [k][n], row stride 40 u16
    __shared__ float    x2p[4][32];        //   512 B: per-wave x2 partials
    __shared__ float    scs[K_], c2s[K_];
    __shared__ float    c2tmp[K_][9];
    __shared__ float    aSumLds[K_];

    unsigned short* xsTs  = (unsigned short*)xsTw;
    unsigned short* A_lds = (unsigned short*)A_ldsw;

    const int tid = threadIdx.x;
    const int l   = tid & 63;
    const int w   = __builtin_amdgcn_readfirstlane(tid >> 6);  // wave 0..3
    const int lc  = l & 31;   // MFMA row/col lane
    const int nh  = l >> 5;   // MFMA k-dim half
    const int b     = blockIdx.x >> 6;
    const int chunk = blockIdx.x & 63;     // 64 chunks of 256 n per batch

    // ---- pre-loop: scale + ||c_k||^2 (fp32), zero aSumLds ----
    {
        int k = tid >> 3, dg = tid & 7;
        const float* cr = Cg + k * D_ + dg * 64;
        float s2 = 0.f;
#pragma unroll
        for (int i = 0; i < 16; ++i) {
            float4 v = *(const float4*)(cr + i * 4);
            s2 += v.x * v.x + v.y * v.y + v.z * v.z + v.w * v.w;
        }
        c2tmp[k][dg] = s2;
        if (tid < K_) { scs[tid] = scale[tid]; aSumLds[tid] = 0.f; }
    }
    __syncthreads();
    if (tid < K_) {
        float s = 0.f;
#pragma unroll
        for (int dg = 0; dg < 8; ++dg) s += c2tmp[tid][dg];
        c2s[tid] = s;
    }

    // ---- preload C fragments (GEMM1 B-operand), per-wave d-steps ----
    // B-frag 32x32x16: B[kdim = 8*(lane/32)+j][col = lane%32] = C[col][d]
    F8 cfr[8];
#pragma unroll
    for (int ss = 0; ss < 8; ++ss) {
        int d0 = (8 * w + ss) * 16 + nh * 8;
        const float* cp = Cg + lc * D_ + d0;
        float4 a  = *(const float4*)(cp);
        float4 bq = *(const float4*)(cp + 4);
        cfr[ss].u[0] = bfpack2(a.x, a.y);
        cfr[ss].u[1] = bfpack2(a.z, a.w);
        cfr[ss].u[2] = bfpack2(bq.x, bq.y);
        cfr[ss].u[3] = bfpack2(bq.z, bq.w);
    }

    f32x16 eacc[4];
#pragma unroll
    for (int ti = 0; ti < 4; ++ti)
#pragma unroll
        for (int r = 0; r < 16; ++r) eacc[ti][r] = 0.f;
    float aSumReg[4] = {0.f, 0.f, 0.f, 0.f};

    // softmax lane mapping: 8 lanes per n, 4 k per lane
    const int nl  = l >> 3;            // 0..7
    const int kq  = l & 7;             // k0 = 4*kq
    const int smn = w * 8 + nl;
    const int k0  = kq * 4;

    const int o  = tid >> 3;  // staging: d-line 0..31 (per r-step: d = o+32r)
    const int nq = tid & 7;   // staging: n-quad
    const size_t xbase = (size_t)b * D_ * N_ + (size_t)chunk * 256;

    // ---- prime the software pipeline: tile 0 loads into registers ----
    float4 pf[16];
    {
        const float* Xp = X + xbase + nq * 4;
#pragma unroll
        for (int r = 0; r < 16; ++r)
            pf[r] = *(const float4*)(Xp + (size_t)(o + 32 * r) * N_);
    }

    for (int t = 0; t < 8; ++t) {
        bar_lds();  // B0: previous tile's GEMM2 done -> xsT reusable

        // ---- stage: prefetched regs -> bf16 LDS + x2 wave partials ----
        {
            float4 x2a; x2a.x = x2a.y = x2a.z = x2a.w = 0.f;
#pragma unroll
            for (int r = 0; r < 16; ++r) {
                int d = o + 32 * r;
                float4 v = pf[r];
                x2a.x += v.x * v.x; x2a.y += v.y * v.y;
                x2a.z += v.z * v.z; x2a.w += v.w * v.w;
                uint2 p;
                p.x = bfpack2(v.x, v.y);
                p.y = bfpack2(v.z, v.w);
                *(uint2*)&xsTw[d * 20 + nq * 2] = p;
            }
            // reduce x2 over the wave's 8 d-line groups (lane bits 3..5)
#pragma unroll
            for (int m = 8; m <= 32; m <<= 1) {
                x2a.x += __shfl_xor(x2a.x, m);
                x2a.y += __shfl_xor(x2a.y, m);
                x2a.z += __shfl_xor(x2a.z, m);
                x2a.w += __shfl_xor(x2a.w, m);
            }
            if (l < 8) *(float4*)&x2p[w][nq * 4] = x2a;
        }

        // ---- issue next tile's global loads (stay in flight across barriers) ----
        {
            int tn = (t < 7) ? t + 1 : 7;
            const float* Xp = X + xbase + tn * 32 + nq * 4;
#pragma unroll
            for (int r = 0; r < 16; ++r)
                pf[r] = *(const float4*)(Xp + (size_t)(o + 32 * r) * N_);
        }

        bar_lds();  // B1: tile + x2 partials visible

        // ---- GEMM1: logits[n][k] d-partials, steps 8w..8w+8 ----
        // A-frag 32x32x16: A[m=lane%32][kdim=8*(lane/32)+j] = X[n=m][d]
        f32x16 lacc;
#pragma unroll
        for (int r = 0; r < 16; ++r) lacc[r] = 0.f;
#pragma unroll
        for (int ss = 0; ss < 8; ++ss) {
            int d0 = (8 * w + ss) * 16 + nh * 8;
            F8 af;
#pragma unroll
            for (int j = 0; j < 8; ++j)
                af.s[j] = xsTs[(d0 + j) * 40 + lc];
            lacc = __builtin_amdgcn_mfma_f32_32x32x16_bf16(af.v, cfr[ss].v, lacc, 0, 0, 0);
        }
        // D: col = lane&31 (=k), row = (reg&3)+8*(reg>>2)+4*(lane>>5) (=n)
#pragma unroll
        for (int r = 0; r < 16; ++r)
            lgp[w][(r & 3) + 8 * (r >> 2) + 4 * nh][lc] = lacc[r];

        bar_lds();  // B2: partials + x2 ready

        // ---- softmax: all waves, 8 lanes per n, 4 k per lane ----
        {
            float4 xc = *(const float4*)&lgp[0][smn][k0];
            float4 x1 = *(const float4*)&lgp[1][smn][k0];
            float4 x2q = *(const float4*)&lgp[2][smn][k0];
            float4 x3 = *(const float4*)&lgp[3][smn][k0];
            xc.x += x1.x + x2q.x + x3.x;
            xc.y += x1.y + x2q.y + x3.y;
            xc.z += x1.z + x2q.z + x3.z;
            xc.w += x1.w + x2q.w + x3.w;
            float x2v = x2p[0][smn] + x2p[1][smn] + x2p[2][smn] + x2p[3][smn];
            float sl0 = scs[k0]     * (x2v - 2.f * xc.x + c2s[k0]);
            float sl1 = scs[k0 + 1] * (x2v - 2.f * xc.y + c2s[k0 + 1]);
            float sl2 = scs[k0 + 2] * (x2v - 2.f * xc.z + c2s[k0 + 2]);
            float sl3 = scs[k0 + 3] * (x2v - 2.f * xc.w + c2s[k0 + 3]);
            float m = fmaxf(fmaxf(sl0, sl1), fmaxf(sl2, sl3));
#pragma unroll
            for (int mk = 1; mk <= 4; mk <<= 1) m = fmaxf(m, __shfl_xor(m, mk));
            float e0 = __expf(sl0 - m), e1 = __expf(sl1 - m);
            float e2 = __expf(sl2 - m), e3 = __expf(sl3 - m);
            float s = e0 + e1 + e2 + e3;
#pragma unroll
            for (int mk = 1; mk <= 4; mk <<= 1) s += __shfl_xor(s, mk);
            float inv = 1.f / s;
            e0 *= inv; e1 *= inv; e2 *= inv; e3 *= inv;
            aSumReg[0] += e0; aSumReg[1] += e1;
            aSumReg[2] += e2; aSumReg[3] += e3;
            A_lds[(k0)     * 40 + smn] = (unsigned short)(bfpack2(e0, 0.f));
            A_lds[(k0 + 1) * 40 + smn] = (unsigned short)(bfpack2(e1, 0.f));
            A_lds[(k0 + 2) * 40 + smn] = (unsigned short)(bfpack2(e2, 0.f));
            A_lds[(k0 + 3) * 40 + smn] = (unsigned short)(bfpack2(e3, 0.f));
        }

        bar_lds();  // B3: A ready

        // ---- GEMM2: E[k][d] += A[k][n] * X[n][d] ----
#pragma unroll
        for (int ti = 0; ti < 4; ++ti) {
            int dcol = (4 * w + ti) * 32 + lc;
#pragma unroll
            for (int ns = 0; ns < 2; ++ns) {
                F8 af, bf;
                af.q = *(const uint4*)&A_lds[lc * 40 + ns * 16 + nh * 8];
                bf.q = *(const uint4*)&xsTs[dcol * 40 + ns * 16 + nh * 8];
                eacc[ti] = __builtin_amdgcn_mfma_f32_32x32x16_bf16(af.v, bf.v, eacc[ti], 0, 0, 0);
            }
        }
    }

    // ---- finalize: plain per-block partial stores (no global atomics) ----
    float* pB = part + (size_t)blockIdx.x * (K_ * D_);
#pragma unroll
    for (int ti = 0; ti < 4; ++ti) {
        int d = (4 * w + ti) * 32 + lc;
#pragma unroll
        for (int r = 0; r < 16; ++r) {
            int k = (r & 3) + 8 * (r >> 2) + 4 * nh;
            pB[k * D_ + d] = eacc[ti][r];
        }
    }

    // aSum: butterfly over the wave's n-lanes, then tiny LDS+global atomics
#pragma unroll
    for (int i = 0; i < 4; ++i) {
#pragma unroll
        for (int m = 8; m <= 32; m <<= 1) aSumReg[i] += __shfl_xor(aSumReg[i], m);
    }
    if (l < 8) {
#pragma unroll
        for (int i = 0; i < 4; ++i) unsafeAtomicAdd(&aSumLds[k0 + i], aSumReg[i]);
    }
    __syncthreads();
    if (tid < K_) unsafeAtomicAdd(&aSumAcc[b * K_ + tid], aSumLds[tid]);
}

// out[b,k,d] = sum_c part[b*64+c][k][d] - aSum[b,k] * C[k,d]
__global__ void finish_kernel(const float* __restrict__ part,
                              const float* __restrict__ aSumAcc,
                              const float* __restrict__ Cg,
                              float* __restrict__ out)
{
    int idx = blockIdx.x * 256 + threadIdx.x;
    int kd = idx & (K_ * D_ - 1);
    int b  = idx >> 14;
    int k  = kd >> 9;
    const float* p = part + (size_t)b * 64 * (K_ * D_) + kd;
    float s = 0.f;
#pragma unroll 8
    for (int c = 0; c < 64; ++c) s += p[(size_t)c * (K_ * D_)];
    out[idx] = s - aSumAcc[(b << 5) + k] * Cg[kd];
}

extern "C" void kernel_launch(void* const* d_in, const int* in_sizes, int n_in,
                              void* d_out, int out_size, void* d_ws, size_t ws_size,
                              hipStream_t stream)
{
    const float* X  = (const float*)d_in[0];
    const float* C  = (const float*)d_in[1];
    const float* sc = (const float*)d_in[2];
    float* out = (float*)d_out;

    float* part    = (float*)d_ws;                    // 512 * K * D fp32 partials (32 MB)
    float* aSumAcc = part + (size_t)512 * K_ * D_;    // B*K fp32

    hipMemsetAsync(aSumAcc, 0, B_ * K_ * sizeof(float), stream);
    encode_kernel<<<B_ * 64, 256, 0, stream>>>(X, C, sc, part, aSumAcc);
    finish_kernel<<<(B_ * K_ * D_) / 256, 256, 0, stream>>>(part, aSumAcc, C, out);
}

// Round 5
// 385.226 us; speedup vs baseline: 1.0018x; 1.0018x over previous
//
#include <hip/hip_runtime.h>
#include <stdint.h>

#define B_ 8
#define D_ 512
#define N_ 16384
#define K_ 32

typedef __attribute__((ext_vector_type(8))) short short8;
typedef __attribute__((ext_vector_type(16))) float f32x16;

union F8 { short8 v; unsigned short s[8]; uint32_t u[4]; uint4 q; };

// RNE pack of two fp32 -> bf16x2 in one u32
__device__ __forceinline__ uint32_t bfpack2(float lo, float hi) {
    uint32_t a = __float_as_uint(lo);
    uint32_t b = __float_as_uint(hi);
    a += 0x7FFFu + ((a >> 16) & 1u);
    b += 0x7FFFu + ((b >> 16) & 1u);
    return (a >> 16) | (b & 0xFFFF0000u);
}
__device__ __forceinline__ unsigned short bf16of(float x) {
    uint32_t a = __float_as_uint(x);
    a += 0x7FFFu + ((a >> 16) & 1u);
    return (unsigned short)(a >> 16);
}
__device__ __forceinline__ float bflo(uint32_t v) { return __uint_as_float(v << 16); }
__device__ __forceinline__ float bfhi(uint32_t v) { return __uint_as_float(v & 0xFFFF0000u); }

// LDS-only barrier (no vmcnt drain; in-loop barriers only order LDS data).
__device__ __forceinline__ void bar_lds() {
    __builtin_amdgcn_s_waitcnt(0xC07F);  // vmcnt=max, expcnt=7, lgkmcnt=0
    __builtin_amdgcn_s_barrier();
}

// 512 threads = 8 waves per block; 2 blocks/CU (66 KB LDS, <=128 VGPR)
// -> 4 waves/SIMD to fill the lockstep latency chains.
// Per block: 256 n (8 tiles of 32) x 512 d; d-work split 8 ways across waves.
__launch_bounds__(512, 4)
__global__ void encode_kernel(const float* __restrict__ X,
                              const float* __restrict__ Cg,
                              const float* __restrict__ scale,
                              float* __restrict__ part,
                              float* __restrict__ aSumAcc)
{
    __shared__ uint32_t xsTw[D_ * 20];       // 40960 B: X^T tile bf16 [d][n], row 40 u16
    __shared__ unsigned short lgpS[8 * 32 * 40]; // 20480 B: GEMM1 d-partials bf16 [w][n][k], row 40
    __shared__ uint32_t A_ldsw[K_ * 20];     //  2560 B: A bf16 [k][n], row 40 u16
    __shared__ float    x2p[8][32];          //  1024 B: per-wave x2 partials
    __shared__ float    scs[K_], c2s[K_];
    __shared__ float    c2tmp[K_][17];       //  2176 B
    __shared__ float    aSumLds[K_];

    unsigned short* xsTs  = (unsigned short*)xsTw;
    unsigned short* A_lds = (unsigned short*)A_ldsw;

    const int tid = threadIdx.x;
    const int l   = tid & 63;
    const int w   = __builtin_amdgcn_readfirstlane(tid >> 6);  // wave 0..7
    const int lc  = l & 31;   // MFMA row/col lane
    const int nh  = l >> 5;   // MFMA k-dim half
    const int b     = blockIdx.x >> 6;
    const int chunk = blockIdx.x & 63;     // 64 chunks of 256 n per batch

    // ---- pre-loop: scale + ||c_k||^2 (fp32), zero aSumLds ----
    {
        int k = tid >> 4, dg = tid & 15;   // 32 k x 16 d-groups of 32
        const float* cr = Cg + k * D_ + dg * 32;
        float s2 = 0.f;
#pragma unroll
        for (int i = 0; i < 8; ++i) {
            float4 v = *(const float4*)(cr + i * 4);
            s2 += v.x * v.x + v.y * v.y + v.z * v.z + v.w * v.w;
        }
        c2tmp[k][dg] = s2;
        if (tid < K_) { scs[tid] = scale[tid]; aSumLds[tid] = 0.f; }
    }
    __syncthreads();
    if (tid < K_) {
        float s = 0.f;
#pragma unroll
        for (int dg = 0; dg < 16; ++dg) s += c2tmp[tid][dg];
        c2s[tid] = s;
    }

    // ---- preload C fragments (GEMM1 B-operand): wave w owns d in [64w,64w+64) ----
    // B-frag 32x32x16: B[kdim = 8*nh+j][col = lc] = C[lc][d0+j]
    F8 cfr[4];
#pragma unroll
    for (int ss = 0; ss < 4; ++ss) {
        int d0 = 64 * w + ss * 16 + nh * 8;
        const float* cp = Cg + lc * D_ + d0;
        float4 a  = *(const float4*)(cp);
        float4 bq = *(const float4*)(cp + 4);
        cfr[ss].u[0] = bfpack2(a.x, a.y);
        cfr[ss].u[1] = bfpack2(a.z, a.w);
        cfr[ss].u[2] = bfpack2(bq.x, bq.y);
        cfr[ss].u[3] = bfpack2(bq.z, bq.w);
    }

    f32x16 eacc[2];
#pragma unroll
    for (int ti = 0; ti < 2; ++ti)
#pragma unroll
        for (int r = 0; r < 16; ++r) eacc[ti][r] = 0.f;
    float aSumReg[4] = {0.f, 0.f, 0.f, 0.f};

    // softmax lane mapping (waves 0..3): 8 lanes per n, 4 k per lane
    const int nl  = l >> 3;
    const int kq  = l & 7;
    const int smn = (w & 3) * 8 + nl;
    const int k0  = kq * 4;

    const int dl = tid >> 3;  // staging d-line 0..63 (d = dl + 64r)
    const int nq = tid & 7;   // staging n-quad
    const size_t xbase = (size_t)b * D_ * N_ + (size_t)chunk * 256;

    for (int t = 0; t < 8; ++t) {
        bar_lds();  // B0: previous tile's GEMM2 done -> xsT reusable

        // ---- stage: global fp32 [d][n] -> bf16 LDS + per-wave x2 ----
        {
            const float* Xp = X + xbase + t * 32 + nq * 4;
            float4 x2a; x2a.x = x2a.y = x2a.z = x2a.w = 0.f;
#pragma unroll
            for (int r = 0; r < 8; ++r) {
                int d = dl + 64 * r;
                float4 v = *(const float4*)(Xp + (size_t)d * N_);
                x2a.x += v.x * v.x; x2a.y += v.y * v.y;
                x2a.z += v.z * v.z; x2a.w += v.w * v.w;
                uint2 p;
                p.x = bfpack2(v.x, v.y);
                p.y = bfpack2(v.z, v.w);
                *(uint2*)&xsTw[d * 20 + nq * 2] = p;
            }
            // reduce x2 over this wave's 8 d-lines (lane bits 3..5)
#pragma unroll
            for (int m = 8; m <= 32; m <<= 1) {
                x2a.x += __shfl_xor(x2a.x, m);
                x2a.y += __shfl_xor(x2a.y, m);
                x2a.z += __shfl_xor(x2a.z, m);
                x2a.w += __shfl_xor(x2a.w, m);
            }
            if (l < 8) *(float4*)&x2p[w][nq * 4] = x2a;
        }

        bar_lds();  // B1: tile + x2 partials visible

        // ---- GEMM1: logits d-partials, wave w covers d in [64w, 64w+64) ----
        // A-frag: A[m=lc][kdim=8*nh+j] = X[n=lc][d0+j]
        {
            f32x16 lacc;
#pragma unroll
            for (int r = 0; r < 16; ++r) lacc[r] = 0.f;
#pragma unroll
            for (int ss = 0; ss < 4; ++ss) {
                int d0 = 64 * w + ss * 16 + nh * 8;
                F8 af;
#pragma unroll
                for (int j = 0; j < 8; ++j)
                    af.s[j] = xsTs[(d0 + j) * 40 + lc];
                lacc = __builtin_amdgcn_mfma_f32_32x32x16_bf16(af.v, cfr[ss].v, lacc, 0, 0, 0);
            }
            // D: col = lc (=k), row = (r&3)+8*(r>>2)+4*nh (=n); store bf16
#pragma unroll
            for (int r = 0; r < 16; ++r) {
                int row = (r & 3) + 8 * (r >> 2) + 4 * nh;
                lgpS[(w * 32 + row) * 40 + lc] = bf16of(lacc[r]);
            }
        }

        bar_lds();  // B2: all d-partials + x2 ready

        // ---- softmax (waves 0..3): 8 lanes per n, 4 k per lane ----
        if (w < 4) {
            float xc0 = 0.f, xc1 = 0.f, xc2 = 0.f, xc3 = 0.f;
#pragma unroll
            for (int wp = 0; wp < 8; ++wp) {
                uint2 pv = *(const uint2*)&lgpS[(wp * 32 + smn) * 40 + k0];
                xc0 += bflo(pv.x); xc1 += bfhi(pv.x);
                xc2 += bflo(pv.y); xc3 += bfhi(pv.y);
            }
            float x2v = 0.f;
#pragma unroll
            for (int wp = 0; wp < 8; ++wp) x2v += x2p[wp][smn];
            float sl0 = scs[k0]     * (x2v - 2.f * xc0 + c2s[k0]);
            float sl1 = scs[k0 + 1] * (x2v - 2.f * xc1 + c2s[k0 + 1]);
            float sl2 = scs[k0 + 2] * (x2v - 2.f * xc2 + c2s[k0 + 2]);
            float sl3 = scs[k0 + 3] * (x2v - 2.f * xc3 + c2s[k0 + 3]);
            float m = fmaxf(fmaxf(sl0, sl1), fmaxf(sl2, sl3));
#pragma unroll
            for (int mk = 1; mk <= 4; mk <<= 1) m = fmaxf(m, __shfl_xor(m, mk));
            float e0 = __expf(sl0 - m), e1 = __expf(sl1 - m);
            float e2 = __expf(sl2 - m), e3 = __expf(sl3 - m);
            float s = e0 + e1 + e2 + e3;
#pragma unroll
            for (int mk = 1; mk <= 4; mk <<= 1) s += __shfl_xor(s, mk);
            float inv = 1.f / s;
            e0 *= inv; e1 *= inv; e2 *= inv; e3 *= inv;
            aSumReg[0] += e0; aSumReg[1] += e1;
            aSumReg[2] += e2; aSumReg[3] += e3;
            A_lds[(k0)     * 40 + smn] = bf16of(e0);
            A_lds[(k0 + 1) * 40 + smn] = bf16of(e1);
            A_lds[(k0 + 2) * 40 + smn] = bf16of(e2);
            A_lds[(k0 + 3) * 40 + smn] = bf16of(e3);
        }

        bar_lds();  // B3: A ready

        // ---- GEMM2: E[k][d] += A[k][n] * X[n][d], wave w d-block [64w,64w+64) ----
#pragma unroll
        for (int ti = 0; ti < 2; ++ti) {
            int dcol = 64 * w + 32 * ti + lc;
#pragma unroll
            for (int ns = 0; ns < 2; ++ns) {
                F8 af, bf;
                af.q = *(const uint4*)&A_lds[lc * 40 + ns * 16 + nh * 8];
                bf.q = *(const uint4*)&xsTs[dcol * 40 + ns * 16 + nh * 8];
                eacc[ti] = __builtin_amdgcn_mfma_f32_32x32x16_bf16(af.v, bf.v, eacc[ti], 0, 0, 0);
            }
        }
    }

    // ---- finalize: plain per-block partial stores (no global atomics) ----
    float* pB = part + (size_t)blockIdx.x * (K_ * D_);
#pragma unroll
    for (int ti = 0; ti < 2; ++ti) {
        int d = 64 * w + 32 * ti + lc;
#pragma unroll
        for (int r = 0; r < 16; ++r) {
            int k = (r & 3) + 8 * (r >> 2) + 4 * nh;
            pB[k * D_ + d] = eacc[ti][r];
        }
    }

    // aSum: reduce over each softmax wave's 8 n-lanes, then LDS + global atomics
    if (w < 4) {
#pragma unroll
        for (int i = 0; i < 4; ++i) {
#pragma unroll
            for (int m = 8; m <= 32; m <<= 1) aSumReg[i] += __shfl_xor(aSumReg[i], m);
        }
        if (l < 8) {
#pragma unroll
            for (int i = 0; i < 4; ++i) unsafeAtomicAdd(&aSumLds[k0 + i], aSumReg[i]);
        }
    }
    __syncthreads();
    if (tid < K_) unsafeAtomicAdd(&aSumAcc[b * K_ + tid], aSumLds[tid]);
}

// out[b,k,d] = sum_c part[b*64+c][k][d] - aSum[b,k] * C[k,d]
__global__ void finish_kernel(const float* __restrict__ part,
                              const float* __restrict__ aSumAcc,
                              const float* __restrict__ Cg,
                              float* __restrict__ out)
{
    int idx = blockIdx.x * 256 + threadIdx.x;
    int kd = idx & (K_ * D_ - 1);
    int b  = idx >> 14;
    int k  = kd >> 9;
    const float* p = part + (size_t)b * 64 * (K_ * D_) + kd;
    float s = 0.f;
#pragma unroll 8
    for (int c = 0; c < 64; ++c) s += p[(size_t)c * (K_ * D_)];
    out[idx] = s - aSumAcc[(b << 5) + k] * Cg[kd];
}

extern "C" void kernel_launch(void* const* d_in, const int* in_sizes, int n_in,
                              void* d_out, int out_size, void* d_ws, size_t ws_size,
                              hipStream_t stream)
{
    const float* X  = (const float*)d_in[0];
    const float* C  = (const float*)d_in[1];
    const float* sc = (const float*)d_in[2];
    float* out = (float*)d_out;

    float* part    = (float*)d_ws;                    // 512 * K * D fp32 partials (32 MB)
    float* aSumAcc = part + (size_t)512 * K_ * D_;    // B*K fp32

    hipMemsetAsync(aSumAcc, 0, B_ * K_ * sizeof(float), stream);
    encode_kernel<<<B_ * 64, 512, 0, stream>>>(X, C, sc, part, aSumAcc);
    finish_kernel<<<(B_ * K_ * D_) / 256, 256, 0, stream>>>(part, aSumAcc, C, out);
}

// Round 6
// 380.405 us; speedup vs baseline: 1.0145x; 1.0127x over previous
//
#include <hip/hip_runtime.h>
#include <stdint.h>

#define B_ 8
#define D_ 512
#define N_ 16384
#define K_ 32

typedef __attribute__((ext_vector_type(8))) short short8;
typedef __attribute__((ext_vector_type(16))) float f32x16;

union F8 { short8 v; unsigned short s[8]; uint32_t u[4]; uint4 q; };

// RNE pack of two fp32 -> bf16x2 in one u32
__device__ __forceinline__ uint32_t bfpack2(float lo, float hi) {
    uint32_t a = __float_as_uint(lo);
    uint32_t b = __float_as_uint(hi);
    a += 0x7FFFu + ((a >> 16) & 1u);
    b += 0x7FFFu + ((b >> 16) & 1u);
    return (a >> 16) | (b & 0xFFFF0000u);
}
__device__ __forceinline__ unsigned short bf16of(float x) {
    uint32_t a = __float_as_uint(x);
    a += 0x7FFFu + ((a >> 16) & 1u);
    return (unsigned short)(a >> 16);
}
__device__ __forceinline__ float bf16tof(unsigned short u) {
    return __uint_as_float(((uint32_t)u) << 16);
}
__device__ __forceinline__ float bflo(uint32_t v) { return __uint_as_float(v << 16); }
__device__ __forceinline__ float bfhi(uint32_t v) { return __uint_as_float(v & 0xFFFF0000u); }

// LDS-only barrier (no vmcnt drain; in-loop barriers only order LDS data).
__device__ __forceinline__ void bar_lds() {
    __builtin_amdgcn_s_waitcnt(0xC07F);  // vmcnt=max, expcnt=7, lgkmcnt=0
    __builtin_amdgcn_s_barrier();
}

// 512 threads = 8 waves per block; 2 blocks/CU (66 KB LDS, <=128 VGPR).
// Per block: 256 n (8 tiles of 32) x 512 d; d-work split 8 ways across waves.
__launch_bounds__(512, 4)
__global__ void encode_kernel(const float* __restrict__ X,
                              const float* __restrict__ Cg,
                              const float* __restrict__ scale,
                              unsigned short* __restrict__ part,
                              float* __restrict__ aSumPart)
{
    __shared__ uint32_t xsTw[D_ * 20];       // 40960 B: X^T tile bf16 [d][n], row 40 u16
    __shared__ unsigned short lgpS[8 * 32 * 40]; // 20480 B: GEMM1 d-partials bf16 [w][n][k]
    __shared__ uint32_t A_ldsw[K_ * 20];     //  2560 B: A bf16 [k][n], row 40 u16
    __shared__ float    x2p[8][32];          //  1024 B: per-wave x2 partials
    __shared__ float    scs[K_], c2s[K_];
    __shared__ float    c2tmp[K_][17];       //  2176 B
    __shared__ float    aSumLds[K_];

    unsigned short* xsTs  = (unsigned short*)xsTw;
    unsigned short* A_lds = (unsigned short*)A_ldsw;

    const int tid = threadIdx.x;
    const int l   = tid & 63;
    const int w   = __builtin_amdgcn_readfirstlane(tid >> 6);  // wave 0..7
    const int lc  = l & 31;   // MFMA row/col lane
    const int nh  = l >> 5;   // MFMA k-dim half
    const int b     = blockIdx.x >> 6;
    const int chunk = blockIdx.x & 63;     // 64 chunks of 256 n per batch

    // ---- pre-loop: scale + ||c_k||^2 (fp32), zero aSumLds ----
    {
        int k = tid >> 4, dg = tid & 15;   // 32 k x 16 d-groups of 32
        const float* cr = Cg + k * D_ + dg * 32;
        float s2 = 0.f;
#pragma unroll
        for (int i = 0; i < 8; ++i) {
            float4 v = *(const float4*)(cr + i * 4);
            s2 += v.x * v.x + v.y * v.y + v.z * v.z + v.w * v.w;
        }
        c2tmp[k][dg] = s2;
        if (tid < K_) { scs[tid] = scale[tid]; aSumLds[tid] = 0.f; }
    }
    __syncthreads();
    if (tid < K_) {
        float s = 0.f;
#pragma unroll
        for (int dg = 0; dg < 16; ++dg) s += c2tmp[tid][dg];
        c2s[tid] = s;
    }

    // ---- preload C fragments (GEMM1 B-operand): wave w owns d in [64w,64w+64) ----
    // B-frag 32x32x16: B[kdim = 8*nh+j][col = lc] = C[lc][d0+j]
    F8 cfr[4];
#pragma unroll
    for (int ss = 0; ss < 4; ++ss) {
        int d0 = 64 * w + ss * 16 + nh * 8;
        const float* cp = Cg + lc * D_ + d0;
        float4 a  = *(const float4*)(cp);
        float4 bq = *(const float4*)(cp + 4);
        cfr[ss].u[0] = bfpack2(a.x, a.y);
        cfr[ss].u[1] = bfpack2(a.z, a.w);
        cfr[ss].u[2] = bfpack2(bq.x, bq.y);
        cfr[ss].u[3] = bfpack2(bq.z, bq.w);
    }

    f32x16 eacc[2];
#pragma unroll
    for (int ti = 0; ti < 2; ++ti)
#pragma unroll
        for (int r = 0; r < 16; ++r) eacc[ti][r] = 0.f;
    float aSumReg[4] = {0.f, 0.f, 0.f, 0.f};

    // softmax lane mapping (waves 0..3): 8 lanes per n, 4 k per lane
    const int nl  = l >> 3;
    const int kq  = l & 7;
    const int smn = (w & 3) * 8 + nl;
    const int k0  = kq * 4;

    const int dl = tid >> 3;  // staging d-line 0..63 (d = dl + 64r)
    const int nq = tid & 7;   // staging n-quad
    const size_t xbase = (size_t)b * D_ * N_ + (size_t)chunk * 256;

    for (int t = 0; t < 8; ++t) {
        bar_lds();  // B0: previous tile's GEMM2 done -> xsT reusable

        // ---- stage: global fp32 [d][n] -> bf16 LDS + per-wave x2 ----
        {
            const float* Xp = X + xbase + t * 32 + nq * 4;
            float4 x2a; x2a.x = x2a.y = x2a.z = x2a.w = 0.f;
#pragma unroll
            for (int r = 0; r < 8; ++r) {
                int d = dl + 64 * r;
                float4 v = *(const float4*)(Xp + (size_t)d * N_);
                x2a.x += v.x * v.x; x2a.y += v.y * v.y;
                x2a.z += v.z * v.z; x2a.w += v.w * v.w;
                uint2 p;
                p.x = bfpack2(v.x, v.y);
                p.y = bfpack2(v.z, v.w);
                *(uint2*)&xsTw[d * 20 + nq * 2] = p;
            }
            // reduce x2 over this wave's 8 d-lines (lane bits 3..5)
#pragma unroll
            for (int m = 8; m <= 32; m <<= 1) {
                x2a.x += __shfl_xor(x2a.x, m);
                x2a.y += __shfl_xor(x2a.y, m);
                x2a.z += __shfl_xor(x2a.z, m);
                x2a.w += __shfl_xor(x2a.w, m);
            }
            if (l < 8) *(float4*)&x2p[w][nq * 4] = x2a;
        }

        bar_lds();  // B1: tile + x2 partials visible

        // ---- GEMM1: logits d-partials, wave w covers d in [64w, 64w+64) ----
        {
            f32x16 lacc;
#pragma unroll
            for (int r = 0; r < 16; ++r) lacc[r] = 0.f;
#pragma unroll
            for (int ss = 0; ss < 4; ++ss) {
                int d0 = 64 * w + ss * 16 + nh * 8;
                F8 af;
#pragma unroll
                for (int j = 0; j < 8; ++j)
                    af.s[j] = xsTs[(d0 + j) * 40 + lc];
                lacc = __builtin_amdgcn_mfma_f32_32x32x16_bf16(af.v, cfr[ss].v, lacc, 0, 0, 0);
            }
            // D: col = lc (=k), row = (r&3)+8*(r>>2)+4*nh (=n); store bf16
#pragma unroll
            for (int r = 0; r < 16; ++r) {
                int row = (r & 3) + 8 * (r >> 2) + 4 * nh;
                lgpS[(w * 32 + row) * 40 + lc] = bf16of(lacc[r]);
            }
        }

        bar_lds();  // B2: all d-partials + x2 ready

        // ---- softmax (waves 0..3): 8 lanes per n, 4 k per lane ----
        if (w < 4) {
            float xc0 = 0.f, xc1 = 0.f, xc2 = 0.f, xc3 = 0.f;
#pragma unroll
            for (int wp = 0; wp < 8; ++wp) {
                uint2 pv = *(const uint2*)&lgpS[(wp * 32 + smn) * 40 + k0];
                xc0 += bflo(pv.x); xc1 += bfhi(pv.x);
                xc2 += bflo(pv.y); xc3 += bfhi(pv.y);
            }
            float x2v = 0.f;
#pragma unroll
            for (int wp = 0; wp < 8; ++wp) x2v += x2p[wp][smn];
            float sl0 = scs[k0]     * (x2v - 2.f * xc0 + c2s[k0]);
            float sl1 = scs[k0 + 1] * (x2v - 2.f * xc1 + c2s[k0 + 1]);
            float sl2 = scs[k0 + 2] * (x2v - 2.f * xc2 + c2s[k0 + 2]);
            float sl3 = scs[k0 + 3] * (x2v - 2.f * xc3 + c2s[k0 + 3]);
            float m = fmaxf(fmaxf(sl0, sl1), fmaxf(sl2, sl3));
#pragma unroll
            for (int mk = 1; mk <= 4; mk <<= 1) m = fmaxf(m, __shfl_xor(m, mk));
            float e0 = __expf(sl0 - m), e1 = __expf(sl1 - m);
            float e2 = __expf(sl2 - m), e3 = __expf(sl3 - m);
            float s = e0 + e1 + e2 + e3;
#pragma unroll
            for (int mk = 1; mk <= 4; mk <<= 1) s += __shfl_xor(s, mk);
            float inv = 1.f / s;
            e0 *= inv; e1 *= inv; e2 *= inv; e3 *= inv;
            aSumReg[0] += e0; aSumReg[1] += e1;
            aSumReg[2] += e2; aSumReg[3] += e3;
            A_lds[(k0)     * 40 + smn] = bf16of(e0);
            A_lds[(k0 + 1) * 40 + smn] = bf16of(e1);
            A_lds[(k0 + 2) * 40 + smn] = bf16of(e2);
            A_lds[(k0 + 3) * 40 + smn] = bf16of(e3);
        }

        bar_lds();  // B3: A ready

        // ---- GEMM2: E[k][d] += A[k][n] * X[n][d], wave w d-block [64w,64w+64) ----
#pragma unroll
        for (int ti = 0; ti < 2; ++ti) {
            int dcol = 64 * w + 32 * ti + lc;
#pragma unroll
            for (int ns = 0; ns < 2; ++ns) {
                F8 af, bf;
                af.q = *(const uint4*)&A_lds[lc * 40 + ns * 16 + nh * 8];
                bf.q = *(const uint4*)&xsTs[dcol * 40 + ns * 16 + nh * 8];
                eacc[ti] = __builtin_amdgcn_mfma_f32_32x32x16_bf16(af.v, bf.v, eacc[ti], 0, 0, 0);
            }
        }
    }

    // ---- finalize: per-block bf16 partial stores (nontemporal, no atomics) ----
    unsigned short* pB = part + (size_t)blockIdx.x * (K_ * D_);
#pragma unroll
    for (int ti = 0; ti < 2; ++ti) {
        int d = 64 * w + 32 * ti + lc;
#pragma unroll
        for (int r = 0; r < 16; ++r) {
            int k = (r & 3) + 8 * (r >> 2) + 4 * nh;
            __builtin_nontemporal_store(bf16of(eacc[ti][r]), &pB[k * D_ + d]);
        }
    }

    // aSum: reduce over each softmax wave's 8 n-lanes, then LDS; plain store
    if (w < 4) {
#pragma unroll
        for (int i = 0; i < 4; ++i) {
#pragma unroll
            for (int m = 8; m <= 32; m <<= 1) aSumReg[i] += __shfl_xor(aSumReg[i], m);
        }
        if (l < 8) {
#pragma unroll
            for (int i = 0; i < 4; ++i) unsafeAtomicAdd(&aSumLds[k0 + i], aSumReg[i]);
        }
    }
    __syncthreads();
    if (tid < K_) aSumPart[blockIdx.x * K_ + tid] = aSumLds[tid];
}

// One block per (b,k,d-half): out[b,k,d] = sum_c part[..] - aSum[b,k]*C[k,d]
__launch_bounds__(256)
__global__ void finish_kernel(const unsigned short* __restrict__ part,
                              const float* __restrict__ aSumPart,
                              const float* __restrict__ Cg,
                              float* __restrict__ out)
{
    __shared__ float sA;
    const int bk = blockIdx.x >> 1;           // 0..255 = b*32+k
    const int b  = bk >> 5;
    const int k  = bk & 31;
    const int d  = (blockIdx.x & 1) * 256 + threadIdx.x;

    if (threadIdx.x < 64) {
        float v = aSumPart[(size_t)((b << 6) + threadIdx.x) * K_ + k];
#pragma unroll
        for (int m = 1; m <= 32; m <<= 1) v += __shfl_xor(v, m);
        if (threadIdx.x == 0) sA = v;
    }
    __syncthreads();

    const unsigned short* p = part + ((size_t)(b * 64) * K_ + k) * D_ + d;
    float s = 0.f;
#pragma unroll 8
    for (int c = 0; c < 64; ++c)
        s += bf16tof(__builtin_nontemporal_load(&p[(size_t)c * (K_ * D_)]));
    out[(size_t)bk * D_ + d] = s - sA * Cg[k * D_ + d];
}

extern "C" void kernel_launch(void* const* d_in, const int* in_sizes, int n_in,
                              void* d_out, int out_size, void* d_ws, size_t ws_size,
                              hipStream_t stream)
{
    const float* X  = (const float*)d_in[0];
    const float* C  = (const float*)d_in[1];
    const float* sc = (const float*)d_in[2];
    float* out = (float*)d_out;

    unsigned short* part = (unsigned short*)d_ws;          // 512*K*D bf16 (16 MB)
    float* aSumPart = (float*)(part + (size_t)512 * K_ * D_);  // 512*K fp32 (64 KB)

    encode_kernel<<<B_ * 64, 512, 0, stream>>>(X, C, sc, part, aSumPart);
    finish_kernel<<<B_ * K_ * 2, 256, 0, stream>>>(part, aSumPart, C, out);
}